// Round 4
// baseline (832.116 us; speedup 1.0000x reference)
//
#include <hip/hip_runtime.h>
#include <math.h>

#define NPTS 262144
#define GBLK (NPTS / 128)     // 2048 gate blocks
#define CPE  2048             // chunks per expert in K2 grid

typedef float f4v __attribute__((ext_vector_type(4)));
typedef short s8v __attribute__((ext_vector_type(8)));

static __device__ __forceinline__ unsigned short f2bf(float f) {
    unsigned u = __float_as_uint(f);
    u += 0x7fffu + ((u >> 16) & 1u);
    return (unsigned short)(u >> 16);
}
static __device__ __forceinline__ unsigned pack2(float lo, float hi) {
    return ((unsigned)f2bf(hi) << 16) | (unsigned)f2bf(lo);
}
static __device__ __forceinline__ float sinrev(float x) {   // sin(2*pi*x)
    return __builtin_amdgcn_sinf(x);
}

union BFrag { uint4 q; unsigned u[4]; s8v s; };

// ---------------- prep: pack A-fragments (pre-scaled bf16 weights) + scaled biases ----------------
// packA frag layout: [(e*3+l)*8 + tau*2+ks][lane][8 bf16], elem i of lane l:
//   row = 16*tau + (l&15), k = 32*ks + 4*(l>>4) + (i<4 ? i : i+12)
__global__ __launch_bounds__(256) void prep_kernel(
    const float* __restrict__ we0, const float* __restrict__ be0,
    const float* __restrict__ wm, const float* __restrict__ bm,
    uint4* __restrict__ packA, float* __restrict__ biasS)
{
    const int idx = blockIdx.x * 256 + threadIdx.x;
    const float PI2I = 0.15915494309189535f;
    if (idx < 12288) {
        const int l = idx & 63;
        const int fr = (idx >> 6) & 7;
        const int grp = idx >> 9;            // e*3 + ell
        const int e = grp / 3, ell = grp % 3;
        const int tau = fr >> 1, ks = fr & 1;
        const int g = l >> 4, m = l & 15;
        const int row = tau * 16 + m;
        const float scale = (ell == 0) ? (22.5f + 45.0f * (float)e) * PI2I : 30.0f * PI2I;
        const float* W = (ell == 0) ? (we0 + e * 4096) : (wm + ((ell - 1) * 8 + e) * 4096);
        unsigned short v[8];
#pragma unroll
        for (int i = 0; i < 8; i++) {
            const int k = 32 * ks + 4 * g + (i < 4 ? i : i + 12);
            v[i] = f2bf(W[row * 64 + k] * scale);
        }
        uint4 q;
        q.x = (unsigned)v[0] | ((unsigned)v[1] << 16);
        q.y = (unsigned)v[2] | ((unsigned)v[3] << 16);
        q.z = (unsigned)v[4] | ((unsigned)v[5] << 16);
        q.w = (unsigned)v[6] | ((unsigned)v[7] << 16);
        packA[idx] = q;
    } else if (idx < 12288 + 1536) {
        const int j = idx - 12288;           // (e*3+ell)*64 + r  == e*192 + ell*64 + r
        const int r = j & 63;
        const int grp = j >> 6;
        const int e = grp / 3, ell = grp % 3;
        const float scale = (ell == 0) ? (22.5f + 45.0f * (float)e) * PI2I : 30.0f * PI2I;
        const float b = (ell == 0) ? be0[e * 64 + r] : bm[((ell - 1) * 8 + e) * 64 + r];
        biasS[j] = b * scale;
    }
}

// ---------------- K1: gate (fp32, pair-split) + top-2 + ballot binning ----------------
__global__ __launch_bounds__(256) void gate_kernel(
    const float* __restrict__ coords,
    const float* __restrict__ fw, const float* __restrict__ fb,
    const float* __restrict__ gw1, const float* __restrict__ gb1,
    const float* __restrict__ lng, const float* __restrict__ lnb,
    const float* __restrict__ gw2, const float* __restrict__ gb2,
    int* __restrict__ counts, int* __restrict__ buckets)
{
    __shared__ float s_fw[192], s_fb[64], s_gb1[64], s_lng[64], s_lnb[64], s_gb2[8];
    __shared__ float s_gw1[4096];
    __shared__ float s_gw2[512];

    const int t = threadIdx.x;
    for (int i = t; i < 4096; i += 256) s_gw1[i] = gw1[i];
    for (int i = t; i < 512; i += 256) s_gw2[i] = gw2[i];
    if (t < 192) s_fw[t] = fw[t];
    if (t < 64) { s_fb[t] = fb[t]; s_gb1[t] = gb1[t]; s_lng[t] = lng[t]; s_lnb[t] = lnb[t]; }
    if (t < 8) s_gb2[t] = gb2[t];
    __syncthreads();

    const int half = t & 1;
    const int p = t >> 1;                       // block-local point 0..127
    const int n = blockIdx.x * 128 + p;
    float f[64];
    {
        const float c0 = coords[n * 3], c1 = coords[n * 3 + 1], c2 = coords[n * 3 + 2];
#pragma unroll
        for (int j = 0; j < 64; j++)
            f[j] = s_fb[j] + c0 * s_fw[j * 3] + c1 * s_fw[j * 3 + 1] + c2 * s_fw[j * 3 + 2];
    }
    float gg[32];
    float mupart = 0.f;
#pragma unroll
    for (int j = 0; j < 32; j++) {
        const int row = j + 32 * half;
        float a = s_gb1[row];
#pragma unroll
        for (int k = 0; k < 64; k += 4) {
            const float4 w = *(const float4*)&s_gw1[row * 64 + k];
            a += f[k] * w.x + f[k + 1] * w.y + f[k + 2] * w.z + f[k + 3] * w.w;
        }
        gg[j] = a; mupart += a;
    }
    const float mu = (mupart + __shfl_xor(mupart, 1, 64)) * (1.f / 64.f);
    float vpart = 0.f;
#pragma unroll
    for (int j = 0; j < 32; j++) { const float d = gg[j] - mu; vpart += d * d; }
    const float var = (vpart + __shfl_xor(vpart, 1, 64)) * (1.f / 64.f);
    const float rs = rsqrtf(var + 1e-5f);
    float logit[8];
#pragma unroll
    for (int e = 0; e < 8; e++) logit[e] = half ? 0.f : s_gb2[e];
#pragma unroll
    for (int j = 0; j < 32; j++) {
        const int row = j + 32 * half;
        const float gn = (gg[j] - mu) * rs * s_lng[row] + s_lnb[row];
#pragma unroll
        for (int e = 0; e < 8; e++) logit[e] += gn * s_gw2[e * 64 + row];
    }
#pragma unroll
    for (int e = 0; e < 8; e++) logit[e] += __shfl_xor(logit[e], 1, 64);
    // top-2 (reference tie semantics: selected iff logit >= 2nd largest)
    float m1 = logit[0]; int i1 = 0;
#pragma unroll
    for (int e = 1; e < 8; e++) if (logit[e] > m1) { m1 = logit[e]; i1 = e; }
    float m2 = -INFINITY;
#pragma unroll
    for (int e = 0; e < 8; e++) if (e != i1 && logit[e] > m2) m2 = logit[e];
    unsigned mbits = 0;
#pragma unroll
    for (int e = 0; e < 8; e++) if (logit[e] >= m2) mbits |= 1u << e;

    // ballot-aggregated bucket insert (one atomic per wave per expert)
    const int lane = t & 63;
#pragma unroll
    for (int e = 0; e < 8; e++) {
        const bool sel = (!half) && ((mbits >> e) & 1u);
        const unsigned long long bal = __ballot(sel);
        int pos0 = 0;
        if (lane == 0) pos0 = atomicAdd(&counts[e], (int)__popcll(bal));
        pos0 = __shfl(pos0, 0, 64);
        if (sel) {
            const int rank = (int)__popcll(bal & ((1ull << lane) - 1ull));
            buckets[e * NPTS + pos0 + rank] = n;
        }
    }
}

// ---------------- K2: per-expert MFMA SIREN on gathered bucket entries ----------------
__global__ __launch_bounds__(256) void expert_kernel(
    const float* __restrict__ coords,
    const float* __restrict__ fw, const float* __restrict__ fb,
    const float* __restrict__ wl, const float* __restrict__ bl,
    const uint4* __restrict__ packA, const float* __restrict__ biasS,
    const int* __restrict__ counts, const int* __restrict__ buckets,
    float* __restrict__ out)
{
    const int e = blockIdx.x >> 11;            // CPE == 2048
    const int chunk = blockIdx.x & (CPE - 1);
    const int cnt = counts[e];
    const int base = chunk * 128;
    if (base >= cnt) return;

    // lane-linear fragment staging: s_ft[region][slot][16B], region=(wv*2+nt)*2+ks, slot=lane
    __shared__ unsigned char s_ft[16 * 1024];
    __shared__ int s_id[128];
    __shared__ float s_b[192];
    __shared__ float s_wl[64];
    __shared__ float s_fw[192];
    __shared__ float s_fb[64];
    __shared__ float s_bl;

    const int t = threadIdx.x;
    // NOTE: all staging covered by t<256 (round-3 bug: s_b tail + s_wl were unloaded)
    if (t < 128) {
        const int gid = base + t;
        s_id[t] = (gid < cnt) ? buckets[e * NPTS + gid] : -1;
    }
    if (t < 192) {
        s_b[t] = biasS[e * 192 + t];
        s_fw[t] = fw[t];
    }
    if (t < 64) {
        s_fb[t] = fb[t];
        s_wl[t] = wl[e * 64 + t];
    }
    if (t == 0) s_bl = bl[e];
    __syncthreads();

    // ---- recompute features for 128 entries (2 threads per entry; no dynamic reg indexing) ----
    const int half = t & 1;
    const int p = t >> 1;
    const int id_p = s_id[p];
    float fh[32];
    if (id_p >= 0) {
        const float c0 = coords[id_p * 3], c1 = coords[id_p * 3 + 1], c2 = coords[id_p * 3 + 2];
        if (half == 0) {
#pragma unroll
            for (int j = 0; j < 32; j++)
                fh[j] = s_fb[j] + c0 * s_fw[j * 3] + c1 * s_fw[j * 3 + 1] + c2 * s_fw[j * 3 + 2];
        } else {
#pragma unroll
            for (int j = 0; j < 32; j++) {
                const int row = j + 32;
                fh[j] = s_fb[row] + c0 * s_fw[row * 3] + c1 * s_fw[row * 3 + 1] + c2 * s_fw[row * 3 + 2];
            }
        }
    } else {
#pragma unroll
        for (int j = 0; j < 32; j++) fh[j] = 0.f;
    }
    {
        const int region = ((p >> 5) * 2 + ((p >> 4) & 1)) * 2 + half;   // (wv*2+nt)*2+ks
        const int slotc = p & 15;
#pragma unroll
        for (int g = 0; g < 4; g++) {
            uint4 q;
            q.x = pack2(fh[4 * g + 0], fh[4 * g + 1]);
            q.y = pack2(fh[4 * g + 2], fh[4 * g + 3]);
            q.z = pack2(fh[4 * g + 16], fh[4 * g + 17]);
            q.w = pack2(fh[4 * g + 18], fh[4 * g + 19]);
            *(uint4*)&s_ft[region * 1024 + (16 * g + slotc) * 16] = q;
        }
    }
    __syncthreads();

    // ---- MFMA phase: each wave handles 32 entries (c=0..15, nt=0..1) ----
    const int lane = t & 63;
    const int wv = t >> 6;
    const int g = lane >> 4, c = lane & 15;
    const int id0 = s_id[wv * 32 + c];
    const int id1 = s_id[wv * 32 + 16 + c];

    BFrag B0[2], B1[2];
#pragma unroll
    for (int ks = 0; ks < 2; ks++) {
        B0[ks].q = *(const uint4*)&s_ft[(((wv * 2 + 0) * 2 + ks) * 1024) + lane * 16];
        B1[ks].q = *(const uint4*)&s_ft[(((wv * 2 + 1) * 2 + ks) * 1024) + lane * 16];
    }

#pragma unroll 1
    for (int ell = 0; ell < 2; ell++) {
        f4v acc0[4], acc1[4];
#pragma unroll
        for (int tau = 0; tau < 4; tau++) {
            const float4 b = *(const float4*)&s_b[ell * 64 + tau * 16 + 4 * g];
            acc0[tau][0] = b.x; acc0[tau][1] = b.y; acc0[tau][2] = b.z; acc0[tau][3] = b.w;
            acc1[tau][0] = b.x; acc1[tau][1] = b.y; acc1[tau][2] = b.z; acc1[tau][3] = b.w;
        }
        const uint4* Ab = packA + (size_t)((e * 3 + ell) * 8) * 64 + lane;
#pragma unroll
        for (int tau = 0; tau < 4; tau++) {
            BFrag A0, A1;
            A0.q = Ab[(tau * 2 + 0) * 64];
            A1.q = Ab[(tau * 2 + 1) * 64];
            acc0[tau] = __builtin_amdgcn_mfma_f32_16x16x32_bf16(A0.s, B0[0].s, acc0[tau], 0, 0, 0);
            acc0[tau] = __builtin_amdgcn_mfma_f32_16x16x32_bf16(A1.s, B0[1].s, acc0[tau], 0, 0, 0);
            acc1[tau] = __builtin_amdgcn_mfma_f32_16x16x32_bf16(A0.s, B1[0].s, acc1[tau], 0, 0, 0);
            acc1[tau] = __builtin_amdgcn_mfma_f32_16x16x32_bf16(A1.s, B1[1].s, acc1[tau], 0, 0, 0);
        }
        // sin + repack: D registers become next layer's B fragments
#pragma unroll
        for (int ks = 0; ks < 2; ks++) {
            B0[ks].u[0] = pack2(sinrev(acc0[2 * ks][0]), sinrev(acc0[2 * ks][1]));
            B0[ks].u[1] = pack2(sinrev(acc0[2 * ks][2]), sinrev(acc0[2 * ks][3]));
            B0[ks].u[2] = pack2(sinrev(acc0[2 * ks + 1][0]), sinrev(acc0[2 * ks + 1][1]));
            B0[ks].u[3] = pack2(sinrev(acc0[2 * ks + 1][2]), sinrev(acc0[2 * ks + 1][3]));
            B1[ks].u[0] = pack2(sinrev(acc1[2 * ks][0]), sinrev(acc1[2 * ks][1]));
            B1[ks].u[1] = pack2(sinrev(acc1[2 * ks][2]), sinrev(acc1[2 * ks][3]));
            B1[ks].u[2] = pack2(sinrev(acc1[2 * ks + 1][0]), sinrev(acc1[2 * ks + 1][1]));
            B1[ks].u[3] = pack2(sinrev(acc1[2 * ks + 1][2]), sinrev(acc1[2 * ks + 1][3]));
        }
    }

    // ---- layer 2 + final dot ----
    {
        f4v acc0[4], acc1[4];
#pragma unroll
        for (int tau = 0; tau < 4; tau++) {
            const float4 b = *(const float4*)&s_b[2 * 64 + tau * 16 + 4 * g];
            acc0[tau][0] = b.x; acc0[tau][1] = b.y; acc0[tau][2] = b.z; acc0[tau][3] = b.w;
            acc1[tau][0] = b.x; acc1[tau][1] = b.y; acc1[tau][2] = b.z; acc1[tau][3] = b.w;
        }
        const uint4* Ab = packA + (size_t)((e * 3 + 2) * 8) * 64 + lane;
#pragma unroll
        for (int tau = 0; tau < 4; tau++) {
            BFrag A0, A1;
            A0.q = Ab[(tau * 2 + 0) * 64];
            A1.q = Ab[(tau * 2 + 1) * 64];
            acc0[tau] = __builtin_amdgcn_mfma_f32_16x16x32_bf16(A0.s, B0[0].s, acc0[tau], 0, 0, 0);
            acc0[tau] = __builtin_amdgcn_mfma_f32_16x16x32_bf16(A1.s, B0[1].s, acc0[tau], 0, 0, 0);
            acc1[tau] = __builtin_amdgcn_mfma_f32_16x16x32_bf16(A0.s, B1[0].s, acc1[tau], 0, 0, 0);
            acc1[tau] = __builtin_amdgcn_mfma_f32_16x16x32_bf16(A1.s, B1[1].s, acc1[tau], 0, 0, 0);
        }
        float px0 = 0.f, px1 = 0.f;
#pragma unroll
        for (int tau = 0; tau < 4; tau++) {
            const float4 w = *(const float4*)&s_wl[tau * 16 + 4 * g];
            px0 += sinrev(acc0[tau][0]) * w.x + sinrev(acc0[tau][1]) * w.y
                 + sinrev(acc0[tau][2]) * w.z + sinrev(acc0[tau][3]) * w.w;
            px1 += sinrev(acc1[tau][0]) * w.x + sinrev(acc1[tau][1]) * w.y
                 + sinrev(acc1[tau][2]) * w.z + sinrev(acc1[tau][3]) * w.w;
        }
        px0 += __shfl_xor(px0, 16, 64); px0 += __shfl_xor(px0, 32, 64);
        px1 += __shfl_xor(px1, 16, 64); px1 += __shfl_xor(px1, 32, 64);
        if (g == 0) {
            if (id0 >= 0) atomicAdd(&out[id0], px0 + s_bl);
            if (id1 >= 0) atomicAdd(&out[id1], px1 + s_bl);
        }
    }
}

// ---------------- aux loss ----------------
__global__ void aux_kernel(const int* __restrict__ counts, float* __restrict__ out)
{
    if (threadIdx.x == 0 && blockIdx.x == 0) {
        double s = 0.0;
        for (int e = 0; e < 8; e++) { const double c = (double)counts[e]; s += c * c; }
        out[NPTS] = (float)(8.0 * s / ((double)NPTS * (double)NPTS));
    }
}

extern "C" void kernel_launch(void* const* d_in, const int* in_sizes, int n_in,
                              void* d_out, int out_size, void* d_ws, size_t ws_size,
                              hipStream_t stream)
{
    const float* coords = (const float*)d_in[0];
    const float* fw  = (const float*)d_in[1];
    const float* fb  = (const float*)d_in[2];
    const float* gw1 = (const float*)d_in[3];
    const float* gb1 = (const float*)d_in[4];
    const float* lng = (const float*)d_in[5];
    const float* lnb = (const float*)d_in[6];
    const float* gw2 = (const float*)d_in[7];
    const float* gb2 = (const float*)d_in[8];
    const float* we0 = (const float*)d_in[9];
    const float* be0 = (const float*)d_in[10];
    const float* wm  = (const float*)d_in[11];
    const float* bm  = (const float*)d_in[12];
    const float* wl  = (const float*)d_in[13];
    const float* bl  = (const float*)d_in[14];
    float* out = (float*)d_out;

    int* counts   = (int*)d_ws;                                   // 64 B
    int* buckets  = (int*)((char*)d_ws + 64);                     // 8*NPTS*4 = 8 MB
    uint4* packA  = (uint4*)((char*)d_ws + 64 + 8 * NPTS * 4);    // 196608 B
    float* biasS  = (float*)((char*)d_ws + 64 + 8 * NPTS * 4 + 196608);  // 6144 B

    hipMemsetAsync(counts, 0, 64, stream);
    hipMemsetAsync(d_out, 0, (size_t)(NPTS + 1) * sizeof(float), stream);

    prep_kernel<<<54, 256, 0, stream>>>(we0, be0, wm, bm, packA, biasS);
    gate_kernel<<<GBLK, 256, 0, stream>>>(coords, fw, fb, gw1, gb1, lng, lnb, gw2, gb2,
                                          counts, buckets);
    expert_kernel<<<8 * CPE, 256, 0, stream>>>(coords, fw, fb, wl, bl, packA, biasS,
                                               counts, buckets, out);
    aux_kernel<<<1, 64, 0, stream>>>(counts, out);
}

// Round 5
// 161.733 us; speedup vs baseline: 5.1450x; 5.1450x over previous
//
#include <hip/hip_runtime.h>
#include <math.h>

#define NPTS 262144
#define GBLK (NPTS / 128)     // 2048 gate blocks
#define CPE  2048             // chunks per expert in K3 grid

typedef float f4v __attribute__((ext_vector_type(4)));
typedef short s8v __attribute__((ext_vector_type(8)));

static __device__ __forceinline__ unsigned short f2bf(float f) {
    unsigned u = __float_as_uint(f);
    u += 0x7fffu + ((u >> 16) & 1u);
    return (unsigned short)(u >> 16);
}
static __device__ __forceinline__ unsigned pack2(float lo, float hi) {
    return ((unsigned)f2bf(hi) << 16) | (unsigned)f2bf(lo);
}
static __device__ __forceinline__ float sinrev(float x) {   // sin(2*pi*x)
    return __builtin_amdgcn_sinf(x);
}

union BFrag { uint4 q; unsigned u[4]; s8v s; };

// ---------------- prep: pack A-fragments (pre-scaled bf16 weights) + scaled biases ----------------
__global__ __launch_bounds__(256) void prep_kernel(
    const float* __restrict__ we0, const float* __restrict__ be0,
    const float* __restrict__ wm, const float* __restrict__ bm,
    uint4* __restrict__ packA, float* __restrict__ biasS)
{
    const int idx = blockIdx.x * 256 + threadIdx.x;
    const float PI2I = 0.15915494309189535f;
    if (idx < 12288) {
        const int l = idx & 63;
        const int fr = (idx >> 6) & 7;
        const int grp = idx >> 9;            // e*3 + ell
        const int e = grp / 3, ell = grp % 3;
        const int tau = fr >> 1, ks = fr & 1;
        const int g = l >> 4, m = l & 15;
        const int row = tau * 16 + m;
        const float scale = (ell == 0) ? (22.5f + 45.0f * (float)e) * PI2I : 30.0f * PI2I;
        const float* W = (ell == 0) ? (we0 + e * 4096) : (wm + ((ell - 1) * 8 + e) * 4096);
        unsigned short v[8];
#pragma unroll
        for (int i = 0; i < 8; i++) {
            const int k = 32 * ks + 4 * g + (i < 4 ? i : i + 12);
            v[i] = f2bf(W[row * 64 + k] * scale);
        }
        uint4 q;
        q.x = (unsigned)v[0] | ((unsigned)v[1] << 16);
        q.y = (unsigned)v[2] | ((unsigned)v[3] << 16);
        q.z = (unsigned)v[4] | ((unsigned)v[5] << 16);
        q.w = (unsigned)v[6] | ((unsigned)v[7] << 16);
        packA[idx] = q;
    } else if (idx < 12288 + 1536) {
        const int j = idx - 12288;           // e*192 + ell*64 + r
        const int r = j & 63;
        const int grp = j >> 6;
        const int e = grp / 3, ell = grp % 3;
        const float scale = (ell == 0) ? (22.5f + 45.0f * (float)e) * PI2I : 30.0f * PI2I;
        const float b = (ell == 0) ? be0[e * 64 + r] : bm[((ell - 1) * 8 + e) * 64 + r];
        biasS[j] = b * scale;
    }
}

// ---------------- K1: gate (fp32, pair-split) -> sel bytes + per-block counts (NO global atomics) ----------------
__global__ __launch_bounds__(256) void gate_kernel(
    const float* __restrict__ coords,
    const float* __restrict__ fw, const float* __restrict__ fb,
    const float* __restrict__ gw1, const float* __restrict__ gb1,
    const float* __restrict__ lng, const float* __restrict__ lnb,
    const float* __restrict__ gw2, const float* __restrict__ gb2,
    unsigned char* __restrict__ sel, int* __restrict__ blkcnt)
{
    __shared__ float s_fw[192], s_fb[64], s_gb1[64], s_lng[64], s_lnb[64], s_gb2[8];
    __shared__ float s_gw1[4096];
    __shared__ float s_gw2[512];
    __shared__ int s_cnt[8];

    const int t = threadIdx.x;
    for (int i = t; i < 4096; i += 256) s_gw1[i] = gw1[i];
    for (int i = t; i < 512; i += 256) s_gw2[i] = gw2[i];
    if (t < 192) s_fw[t] = fw[t];
    if (t < 64) { s_fb[t] = fb[t]; s_gb1[t] = gb1[t]; s_lng[t] = lng[t]; s_lnb[t] = lnb[t]; }
    if (t < 8) { s_gb2[t] = gb2[t]; s_cnt[t] = 0; }
    __syncthreads();

    const int half = t & 1;
    const int p = t >> 1;                       // block-local point 0..127
    const int n = blockIdx.x * 128 + p;
    float f[64];
    {
        const float c0 = coords[n * 3], c1 = coords[n * 3 + 1], c2 = coords[n * 3 + 2];
#pragma unroll
        for (int j = 0; j < 64; j++)
            f[j] = s_fb[j] + c0 * s_fw[j * 3] + c1 * s_fw[j * 3 + 1] + c2 * s_fw[j * 3 + 2];
    }
    float gg[32];
    float mupart = 0.f;
#pragma unroll
    for (int j = 0; j < 32; j++) {
        const int row = j + 32 * half;
        float a = s_gb1[row];
#pragma unroll
        for (int k = 0; k < 64; k += 4) {
            const float4 w = *(const float4*)&s_gw1[row * 64 + k];
            a += f[k] * w.x + f[k + 1] * w.y + f[k + 2] * w.z + f[k + 3] * w.w;
        }
        gg[j] = a; mupart += a;
    }
    const float mu = (mupart + __shfl_xor(mupart, 1, 64)) * (1.f / 64.f);
    float vpart = 0.f;
#pragma unroll
    for (int j = 0; j < 32; j++) { const float d = gg[j] - mu; vpart += d * d; }
    const float var = (vpart + __shfl_xor(vpart, 1, 64)) * (1.f / 64.f);
    const float rs = rsqrtf(var + 1e-5f);
    float logit[8];
#pragma unroll
    for (int e = 0; e < 8; e++) logit[e] = half ? 0.f : s_gb2[e];
#pragma unroll
    for (int j = 0; j < 32; j++) {
        const int row = j + 32 * half;
        const float gn = (gg[j] - mu) * rs * s_lng[row] + s_lnb[row];
#pragma unroll
        for (int e = 0; e < 8; e++) logit[e] += gn * s_gw2[e * 64 + row];
    }
#pragma unroll
    for (int e = 0; e < 8; e++) logit[e] += __shfl_xor(logit[e], 1, 64);
    // top-2 (reference tie semantics: selected iff logit >= 2nd largest)
    float m1 = logit[0]; int i1 = 0;
#pragma unroll
    for (int e = 1; e < 8; e++) if (logit[e] > m1) { m1 = logit[e]; i1 = e; }
    float m2 = -INFINITY;
#pragma unroll
    for (int e = 0; e < 8; e++) if (e != i1 && logit[e] > m2) m2 = logit[e];
    unsigned mbits = 0;
#pragma unroll
    for (int e = 0; e < 8; e++) if (logit[e] >= m2) mbits |= 1u << e;

    if (!half) sel[n] = (unsigned char)mbits;

    const int lane = t & 63;
#pragma unroll
    for (int e = 0; e < 8; e++) {
        const unsigned long long bal = __ballot((!half) && ((mbits >> e) & 1u));
        if (lane == 0) atomicAdd(&s_cnt[e], (int)__popcll(bal));   // LDS only
    }
    __syncthreads();
    if (t < 8) blkcnt[blockIdx.x * 8 + t] = s_cnt[t];
}

// ---------------- K1.5: single-block scan -> baseoff, counts, aux ----------------
__global__ __launch_bounds__(256) void scan_kernel(
    const int* __restrict__ blkcnt, int* __restrict__ baseoff,
    int* __restrict__ counts, float* __restrict__ out)
{
    __shared__ int s_tot[8];
    const int t = threadIdx.x;
    const int e = t >> 5;        // 8 experts x 32 lanes (32-aligned groups)
    const int q = t & 31;
    const int b0 = q * (GBLK / 32);
    int partial = 0;
    for (int b = b0; b < b0 + GBLK / 32; b++) partial += blkcnt[b * 8 + e];
    int incl = partial;
#pragma unroll
    for (int d = 1; d < 32; d <<= 1) {
        const int v = __shfl_up(incl, d, 32);
        if (q >= d) incl += v;
    }
    const int excl = incl - partial;
    const int total = __shfl(incl, 31, 32);
    if (q == 0) { counts[e] = total; s_tot[e] = total; }
    int run = excl;
    for (int b = b0; b < b0 + GBLK / 32; b++) {
        baseoff[b * 8 + e] = run;
        run += blkcnt[b * 8 + e];
    }
    __syncthreads();
    if (t == 0) {
        double s = 0.0;
        for (int i = 0; i < 8; i++) { const double c = (double)s_tot[i]; s += c * c; }
        out[NPTS] = (float)(8.0 * s / ((double)NPTS * (double)NPTS));
    }
}

// ---------------- K2: scatter points into buckets (no atomics) ----------------
__global__ __launch_bounds__(128) void scatter_kernel(
    const unsigned char* __restrict__ sel, const int* __restrict__ baseoff,
    int* __restrict__ buckets)
{
    __shared__ int s_w0[8];
    const int t = threadIdx.x;
    const int n = blockIdx.x * 128 + t;
    const unsigned m = sel[n];
    const int w = t >> 6, lane = t & 63;
    unsigned long long bal[8];
#pragma unroll
    for (int e = 0; e < 8; e++) {
        bal[e] = __ballot((m >> e) & 1u);
        if (w == 0 && lane == 0) s_w0[e] = (int)__popcll(bal[e]);
    }
    __syncthreads();
#pragma unroll
    for (int e = 0; e < 8; e++) {
        if ((m >> e) & 1u) {
            int rank = (int)__popcll(bal[e] & ((1ull << lane) - 1ull));
            if (w == 1) rank += s_w0[e];
            buckets[e * NPTS + baseoff[blockIdx.x * 8 + e] + rank] = n;
        }
    }
}

// ---------------- K3: per-expert MFMA SIREN on gathered bucket entries ----------------
__global__ __launch_bounds__(256) void expert_kernel(
    const float* __restrict__ coords,
    const float* __restrict__ fw, const float* __restrict__ fb,
    const float* __restrict__ wl, const float* __restrict__ bl,
    const uint4* __restrict__ packA, const float* __restrict__ biasS,
    const int* __restrict__ counts, const int* __restrict__ buckets,
    float* __restrict__ out)
{
    const int e = blockIdx.x >> 11;            // CPE == 2048
    const int chunk = blockIdx.x & (CPE - 1);
    const int cnt = counts[e];
    const int base = chunk * 128;
    if (base >= cnt) return;

    __shared__ unsigned char s_ft[16 * 1024];
    __shared__ int s_id[128];
    __shared__ float s_b[192];
    __shared__ float s_wl[64];
    __shared__ float s_fw[192];
    __shared__ float s_fb[64];
    __shared__ float s_bl;

    const int t = threadIdx.x;
    if (t < 128) {
        const int gid = base + t;
        s_id[t] = (gid < cnt) ? buckets[e * NPTS + gid] : -1;
    }
    if (t < 192) {
        s_b[t] = biasS[e * 192 + t];
        s_fw[t] = fw[t];
    }
    if (t < 64) {
        s_fb[t] = fb[t];
        s_wl[t] = wl[e * 64 + t];
    }
    if (t == 0) s_bl = bl[e];
    __syncthreads();

    // ---- recompute features for 128 entries (2 threads per entry) ----
    const int half = t & 1;
    const int p = t >> 1;
    const int id_p = s_id[p];
    float fh[32];
    if (id_p >= 0) {
        const float c0 = coords[id_p * 3], c1 = coords[id_p * 3 + 1], c2 = coords[id_p * 3 + 2];
        if (half == 0) {
#pragma unroll
            for (int j = 0; j < 32; j++)
                fh[j] = s_fb[j] + c0 * s_fw[j * 3] + c1 * s_fw[j * 3 + 1] + c2 * s_fw[j * 3 + 2];
        } else {
#pragma unroll
            for (int j = 0; j < 32; j++) {
                const int row = j + 32;
                fh[j] = s_fb[row] + c0 * s_fw[row * 3] + c1 * s_fw[row * 3 + 1] + c2 * s_fw[row * 3 + 2];
            }
        }
    } else {
#pragma unroll
        for (int j = 0; j < 32; j++) fh[j] = 0.f;
    }
    {
        const int region = ((p >> 5) * 2 + ((p >> 4) & 1)) * 2 + half;   // (wv*2+nt)*2+ks
        const int slotc = p & 15;
#pragma unroll
        for (int g = 0; g < 4; g++) {
            uint4 q;
            q.x = pack2(fh[4 * g + 0], fh[4 * g + 1]);
            q.y = pack2(fh[4 * g + 2], fh[4 * g + 3]);
            q.z = pack2(fh[4 * g + 16], fh[4 * g + 17]);
            q.w = pack2(fh[4 * g + 18], fh[4 * g + 19]);
            *(uint4*)&s_ft[region * 1024 + (16 * g + slotc) * 16] = q;
        }
    }
    __syncthreads();

    // ---- MFMA phase: each wave handles 32 entries ----
    const int lane = t & 63;
    const int wv = t >> 6;
    const int g = lane >> 4, c = lane & 15;
    const int id0 = s_id[wv * 32 + c];
    const int id1 = s_id[wv * 32 + 16 + c];

    BFrag B0[2], B1[2];
#pragma unroll
    for (int ks = 0; ks < 2; ks++) {
        B0[ks].q = *(const uint4*)&s_ft[(((wv * 2 + 0) * 2 + ks) * 1024) + lane * 16];
        B1[ks].q = *(const uint4*)&s_ft[(((wv * 2 + 1) * 2 + ks) * 1024) + lane * 16];
    }

#pragma unroll 1
    for (int ell = 0; ell < 2; ell++) {
        f4v acc0[4], acc1[4];
#pragma unroll
        for (int tau = 0; tau < 4; tau++) {
            const float4 b = *(const float4*)&s_b[ell * 64 + tau * 16 + 4 * g];
            acc0[tau][0] = b.x; acc0[tau][1] = b.y; acc0[tau][2] = b.z; acc0[tau][3] = b.w;
            acc1[tau][0] = b.x; acc1[tau][1] = b.y; acc1[tau][2] = b.z; acc1[tau][3] = b.w;
        }
        const uint4* Ab = packA + (size_t)((e * 3 + ell) * 8) * 64 + lane;
#pragma unroll
        for (int tau = 0; tau < 4; tau++) {
            BFrag A0, A1;
            A0.q = Ab[(tau * 2 + 0) * 64];
            A1.q = Ab[(tau * 2 + 1) * 64];
            acc0[tau] = __builtin_amdgcn_mfma_f32_16x16x32_bf16(A0.s, B0[0].s, acc0[tau], 0, 0, 0);
            acc0[tau] = __builtin_amdgcn_mfma_f32_16x16x32_bf16(A1.s, B0[1].s, acc0[tau], 0, 0, 0);
            acc1[tau] = __builtin_amdgcn_mfma_f32_16x16x32_bf16(A0.s, B1[0].s, acc1[tau], 0, 0, 0);
            acc1[tau] = __builtin_amdgcn_mfma_f32_16x16x32_bf16(A1.s, B1[1].s, acc1[tau], 0, 0, 0);
        }
#pragma unroll
        for (int ks = 0; ks < 2; ks++) {
            B0[ks].u[0] = pack2(sinrev(acc0[2 * ks][0]), sinrev(acc0[2 * ks][1]));
            B0[ks].u[1] = pack2(sinrev(acc0[2 * ks][2]), sinrev(acc0[2 * ks][3]));
            B0[ks].u[2] = pack2(sinrev(acc0[2 * ks + 1][0]), sinrev(acc0[2 * ks + 1][1]));
            B0[ks].u[3] = pack2(sinrev(acc0[2 * ks + 1][2]), sinrev(acc0[2 * ks + 1][3]));
            B1[ks].u[0] = pack2(sinrev(acc1[2 * ks][0]), sinrev(acc1[2 * ks][1]));
            B1[ks].u[1] = pack2(sinrev(acc1[2 * ks][2]), sinrev(acc1[2 * ks][3]));
            B1[ks].u[2] = pack2(sinrev(acc1[2 * ks + 1][0]), sinrev(acc1[2 * ks + 1][1]));
            B1[ks].u[3] = pack2(sinrev(acc1[2 * ks + 1][2]), sinrev(acc1[2 * ks + 1][3]));
        }
    }

    // ---- layer 2 + final dot ----
    {
        f4v acc0[4], acc1[4];
#pragma unroll
        for (int tau = 0; tau < 4; tau++) {
            const float4 b = *(const float4*)&s_b[2 * 64 + tau * 16 + 4 * g];
            acc0[tau][0] = b.x; acc0[tau][1] = b.y; acc0[tau][2] = b.z; acc0[tau][3] = b.w;
            acc1[tau][0] = b.x; acc1[tau][1] = b.y; acc1[tau][2] = b.z; acc1[tau][3] = b.w;
        }
        const uint4* Ab = packA + (size_t)((e * 3 + 2) * 8) * 64 + lane;
#pragma unroll
        for (int tau = 0; tau < 4; tau++) {
            BFrag A0, A1;
            A0.q = Ab[(tau * 2 + 0) * 64];
            A1.q = Ab[(tau * 2 + 1) * 64];
            acc0[tau] = __builtin_amdgcn_mfma_f32_16x16x32_bf16(A0.s, B0[0].s, acc0[tau], 0, 0, 0);
            acc0[tau] = __builtin_amdgcn_mfma_f32_16x16x32_bf16(A1.s, B0[1].s, acc0[tau], 0, 0, 0);
            acc1[tau] = __builtin_amdgcn_mfma_f32_16x16x32_bf16(A0.s, B1[0].s, acc1[tau], 0, 0, 0);
            acc1[tau] = __builtin_amdgcn_mfma_f32_16x16x32_bf16(A1.s, B1[1].s, acc1[tau], 0, 0, 0);
        }
        float px0 = 0.f, px1 = 0.f;
#pragma unroll
        for (int tau = 0; tau < 4; tau++) {
            const float4 w = *(const float4*)&s_wl[tau * 16 + 4 * g];
            px0 += sinrev(acc0[tau][0]) * w.x + sinrev(acc0[tau][1]) * w.y
                 + sinrev(acc0[tau][2]) * w.z + sinrev(acc0[tau][3]) * w.w;
            px1 += sinrev(acc1[tau][0]) * w.x + sinrev(acc1[tau][1]) * w.y
                 + sinrev(acc1[tau][2]) * w.z + sinrev(acc1[tau][3]) * w.w;
        }
        px0 += __shfl_xor(px0, 16, 64); px0 += __shfl_xor(px0, 32, 64);
        px1 += __shfl_xor(px1, 16, 64); px1 += __shfl_xor(px1, 32, 64);
        if (g == 0) {
            if (id0 >= 0) atomicAdd(&out[id0], px0 + s_bl);
            if (id1 >= 0) atomicAdd(&out[id1], px1 + s_bl);
        }
    }
}

extern "C" void kernel_launch(void* const* d_in, const int* in_sizes, int n_in,
                              void* d_out, int out_size, void* d_ws, size_t ws_size,
                              hipStream_t stream)
{
    const float* coords = (const float*)d_in[0];
    const float* fw  = (const float*)d_in[1];
    const float* fb  = (const float*)d_in[2];
    const float* gw1 = (const float*)d_in[3];
    const float* gb1 = (const float*)d_in[4];
    const float* lng = (const float*)d_in[5];
    const float* lnb = (const float*)d_in[6];
    const float* gw2 = (const float*)d_in[7];
    const float* gb2 = (const float*)d_in[8];
    const float* we0 = (const float*)d_in[9];
    const float* be0 = (const float*)d_in[10];
    const float* wm  = (const float*)d_in[11];
    const float* bm  = (const float*)d_in[12];
    const float* wl  = (const float*)d_in[13];
    const float* bl  = (const float*)d_in[14];
    float* out = (float*)d_out;

    char* ws = (char*)d_ws;
    int* counts           = (int*)ws;                        // 64 B
    int* buckets          = (int*)(ws + 64);                 // 8*NPTS*4 = 8388608
    uint4* packA          = (uint4*)(ws + 8388672);          // 196608
    float* biasS          = (float*)(ws + 8585280);          // 6144
    int* blkcnt           = (int*)(ws + 8591424);            // GBLK*8*4 = 65536
    int* baseoff          = (int*)(ws + 8656960);            // 65536
    unsigned char* sel    = (unsigned char*)(ws + 8722496);  // NPTS = 262144

    hipMemsetAsync(d_out, 0, (size_t)(NPTS + 1) * sizeof(float), stream);

    prep_kernel<<<54, 256, 0, stream>>>(we0, be0, wm, bm, packA, biasS);
    gate_kernel<<<GBLK, 256, 0, stream>>>(coords, fw, fb, gw1, gb1, lng, lnb, gw2, gb2,
                                          sel, blkcnt);
    scan_kernel<<<1, 256, 0, stream>>>(blkcnt, baseoff, counts, out);
    scatter_kernel<<<GBLK, 128, 0, stream>>>(sel, baseoff, buckets);
    expert_kernel<<<8 * CPE, 256, 0, stream>>>(coords, fw, fb, wl, bl, packA, biasS,
                                               counts, buckets, out);
}